// Round 7
// baseline (243.562 us; speedup 1.0000x reference)
//
#include <hip/hip_runtime.h>
#include <cstdint>

// ---------------- ws layout (bytes) ----------------
#define OFF_W1T   0          // [784][256] f32   802816 B
#define OFF_W2T   802816     // [256][128] f32   131072 B
#define OFF_H3T   933888     // [784][4096] f32  12845056 B
// total 13778944 B

__device__ __forceinline__ uint32_t bfe3(uint32_t r, int j) { return (r >> j) & 7u; }

// ---------------- conv stack: 4 images per block; self-contained -----------
// Prologue: grid-stride transpose of fc1_w/fc2_w into w1T/w2T (for fc_stack),
// and per-block packing of conv weight sign bits into LDS.
__global__ __launch_bounds__(256, 4) void conv_stack(
    const float* __restrict__ x, const float* __restrict__ b1,
    const float* __restrict__ b2, const float* __restrict__ b3,
    const float* __restrict__ w1, const float* __restrict__ w2,
    const float* __restrict__ w3,
    const float* __restrict__ fc1_w, const float* __restrict__ fc2_w,
    float* __restrict__ w1T, float* __restrict__ w2T,
    float* __restrict__ h3T) {
    __shared__ __align__(16) uint32_t s_H1[4][16][16];
    __shared__ __align__(16) uint32_t s_H2[4][9][9][2];
    __shared__ uint32_t s_xr[4][32];
    __shared__ uint32_t s_w1[32];
    __shared__ int s_sth1[32], s_ic1[32], s_ic2[64];
    __shared__ uint32_t s_W2t[9][64];
    __shared__ uint32_t s_W3t[18][16];
    __shared__ float s_b3[16];

    const int t = threadIdx.x;
    const int lane = t & 63;
    const int wid = t >> 6;
    const int img0 = blockIdx.x * 4;

    // ---- grid-stride FC weight transpose (233472 elements over 262144 thr) --
    {
        int e = blockIdx.x * 256 + t;
        if (e < 200704) {                 // w1T [784][256]
            int k = e >> 8, n = e & 255;
            w1T[e] = fc1_w[n * 784 + k];
        } else if (e < 233472) {          // w2T [256][128]
            int e2 = e - 200704;
            int k = e2 >> 7, n = e2 & 127;
            w2T[e2] = fc2_w[n * 256 + k];
        }
    }

    // ---- setup ----
    {
        uint32_t* h1f = &s_H1[0][0][0];
        for (int i = t; i < 1024; i += 256) h1f[i] = 0;
        uint32_t* h2f = &s_H2[0][0][0][0];
        for (int i = t; i < 648; i += 256) h2f[i] = 0;
    }
    if (t < 32) {
        uint32_t b = 0;
#pragma unroll
        for (int k = 0; k < 9; ++k) b |= (w1[t * 9 + k] > 0.f ? 1u : 0u) << k;
        s_w1[t] = b;
        int ic = (int)floorf(-b1[t]) + 1;
        s_ic1[t] = ic;
        s_sth1[t] = (9 - ic) >> 1;
    } else if (t < 96) {
        s_ic2[t - 32] = (int)floorf(-b2[t - 32]) + 1;
    } else if (t < 112) {
        s_b3[t - 96] = b3[t - 96];
    } else if (t >= 128 && t < 240) {
        int r = t - 128;
        int im = r / 28, row = r - im * 28;
        const float4* xr = (const float4*)(x + (img0 + im) * 784 + row * 28);
        uint32_t b = 0;
#pragma unroll
        for (int q = 0; q < 7; ++q) {
            float4 v = xr[q];
            b |= (v.x > 0.f ? 1u : 0u) << (q * 4 + 0);
            b |= (v.y > 0.f ? 1u : 0u) << (q * 4 + 1);
            b |= (v.z > 0.f ? 1u : 0u) << (q * 4 + 2);
            b |= (v.w > 0.f ? 1u : 0u) << (q * 4 + 3);
        }
        s_xr[im][row] = b << 1;
    }
    // pack w2 bits: s_W2t[tap][oc], bit ic = w2[oc*288 + ic*9 + tap] > 0
    for (int i = t; i < 576; i += 256) {
        int tap = i >> 6, oc = i & 63;
        const float* wp = w2 + oc * 288 + tap;
        uint32_t b = 0;
#pragma unroll
        for (int ic = 0; ic < 32; ++ic)
            b |= (wp[ic * 9] > 0.f ? 1u : 0u) << ic;
        s_W2t[tap][oc] = b;
    }
    // pack w3 bits: s_W3t[tap*2+half][oc], bit ic = w3[oc*576+half*288+ic*9+tap]
    for (int i = t; i < 288; i += 256) {
        int w18 = i >> 4, oc = i & 15;
        int tap = w18 >> 1, half = w18 & 1;
        const float* wp = w3 + oc * 576 + half * 288 + tap;
        uint32_t b = 0;
#pragma unroll
        for (int ic = 0; ic < 32; ++ic)
            b |= (wp[ic * 9] > 0.f ? 1u : 0u) << ic;
        s_W3t[w18][oc] = b;
    }
    __syncthreads();

    // ---- conv1: 784 tasks = 196 pos x 4 img ----
    for (int task = t; task < 784; task += 256) {
        int im = task & 3, pid = task >> 2;
        int pi, pj;
        if (pid < 144) { pi = 1 + pid / 12; pj = 1 + pid - (pid / 12) * 12; }
        else {
            int b = pid - 144;
            if (b < 14)      { pi = 0;  pj = b; }
            else if (b < 28) { pi = 13; pj = b - 14; }
            else if (b < 40) { pi = 1 + (b - 28); pj = 0; }
            else             { pi = 1 + (b - 40); pj = 13; }
        }
        const uint32_t* xr = &s_xr[im][0];
        int y0 = 2 * pi - 1;
        uint32_t r0 = (pi > 0)  ? xr[y0]     : 0u;
        uint32_t r1 = xr[y0 + 1];
        uint32_t r2 = xr[y0 + 2];
        uint32_t r3 = (pi < 13) ? xr[y0 + 3] : 0u;
        int j0 = 2 * pj, j1 = 2 * pj + 1;
        uint32_t s00 = bfe3(r0, j0) | (bfe3(r1, j0) << 3) | (bfe3(r2, j0) << 6);
        uint32_t s01 = bfe3(r0, j1) | (bfe3(r1, j1) << 3) | (bfe3(r2, j1) << 6);
        uint32_t s10 = bfe3(r1, j0) | (bfe3(r2, j0) << 3) | (bfe3(r3, j0) << 6);
        uint32_t s11 = bfe3(r1, j1) | (bfe3(r2, j1) << 3) | (bfe3(r3, j1) << 6);
        uint32_t word = 0;
        if (pid < 144) {
#pragma unroll 4
            for (int c = 0; c < 32; ++c) {
                uint32_t w = s_w1[c];
                int S = min(min(__popc(s00 ^ w), __popc(s01 ^ w)),
                            min(__popc(s10 ^ w), __popc(s11 ^ w)));
                word |= (uint32_t)(S <= s_sth1[c]) << c;
            }
        } else {
            uint32_t iT = (pi == 0)  ? 0x7u   : 0u;
            uint32_t iB = (pi == 13) ? 0x1C0u : 0u;
            uint32_t iL = (pj == 0)  ? 0x49u  : 0u;
            uint32_t iR = (pj == 13) ? 0x124u : 0u;
            uint32_t i00 = iT | iL, i01 = iT | iR, i10 = iB | iL, i11 = iB | iR;
            int n00 = 9 - __popc(i00), n01 = 9 - __popc(i01);
            int n10 = 9 - __popc(i10), n11 = 9 - __popc(i11);
#pragma unroll 4
            for (int c = 0; c < 32; ++c) {
                uint32_t w = s_w1[c];
                int v0 = n00 - 2 * (__popc(s00 ^ w) - __popc(w & i00));
                int v1 = n01 - 2 * (__popc(s01 ^ w) - __popc(w & i01));
                int v2 = n10 - 2 * (__popc(s10 ^ w) - __popc(w & i10));
                int v3 = n11 - 2 * (__popc(s11 ^ w) - __popc(w & i11));
                int vm = max(max(v0, v1), max(v2, v3));
                word |= (uint32_t)(vm >= s_ic1[c]) << c;
            }
        }
        s_H1[im][pi + 1][pj + 1] = word;
    }
    __syncthreads();

    // ---- conv2: wave per image; lane = oc; C[4][16] register window ----
    {
        const int im = wid;
        uint32_t wv[9];
#pragma unroll
        for (int k = 0; k < 9; ++k) wv[k] = s_W2t[k][lane];
        int ic2 = s_ic2[lane];
        int sth2 = (288 - ic2) >> 1;
        int pc0 = __popc(wv[0]), pc2 = __popc(wv[2]);
        int pc6 = __popc(wv[6]), pc8 = __popc(wv[8]);
        int topc = pc0 + __popc(wv[1]) + pc2;
        int botc = pc6 + __popc(wv[7]) + pc8;
        int lefc = pc0 + __popc(wv[3]) + pc6;
        int rigc = pc2 + __popc(wv[5]) + pc8;
        const uint32_t* plane = &s_H1[im][0][0];

        for (int pi = 0; pi < 7; ++pi) {
            uint32_t C[4][16];
#pragma unroll
            for (int r = 0; r < 4; ++r) {
                const uint32_t* rp = &plane[(2 * pi + r) * 16];
                *(uint4*)&C[r][0]  = *(const uint4*)&rp[0];
                *(uint4*)&C[r][4]  = *(const uint4*)&rp[4];
                *(uint4*)&C[r][8]  = *(const uint4*)&rp[8];
                *(uint4*)&C[r][12] = *(const uint4*)&rp[12];
            }
            const int rT = (pi == 0), rB = (pi == 6);
#pragma unroll
            for (int pj = 0; pj < 7; ++pj) {
                int S00 = 0, S01 = 0, S10 = 0, S11 = 0;
#pragma unroll
                for (int kh = 0; kh < 3; ++kh)
#pragma unroll
                    for (int kw = 0; kw < 3; ++kw) {
                        uint32_t ww = wv[kh * 3 + kw];
                        S00 += __popc(C[kh][2 * pj + kw] ^ ww);
                        S01 += __popc(C[kh][2 * pj + 1 + kw] ^ ww);
                        S10 += __popc(C[kh + 1][2 * pj + kw] ^ ww);
                        S11 += __popc(C[kh + 1][2 * pj + 1 + kw] ^ ww);
                    }
                int pred;
                if (pj >= 1 && pj <= 5) {
                    if (!rT && !rB) {
                        int Sm = min(min(S00, S01), min(S10, S11));
                        pred = (Sm <= sth2);
                    } else if (rT) {
                        int v0 = 192 - 2 * (S00 - topc);
                        int v1 = 192 - 2 * (S01 - topc);
                        int v2 = 288 - 2 * S10;
                        int v3 = 288 - 2 * S11;
                        pred = (max(max(v0, v1), max(v2, v3)) >= ic2);
                    } else {
                        int v0 = 288 - 2 * S00;
                        int v1 = 288 - 2 * S01;
                        int v2 = 192 - 2 * (S10 - botc);
                        int v3 = 192 - 2 * (S11 - botc);
                        pred = (max(max(v0, v1), max(v2, v3)) >= ic2);
                    }
                } else {
                    const int cL = (pj == 0), cR = (pj == 6);
                    int v0, v1, v2, v3;
                    { int rI = rT, cI = cL;
                      int corr = (rI ? topc : 0) + (cI ? lefc : 0) - ((rI & cI) ? pc0 : 0);
                      int nv = 32 * (9 - 3 * rI - 3 * cI + (rI & cI));
                      v0 = nv - 2 * (S00 - corr); }
                    { int rI = rT, cI = cR;
                      int corr = (rI ? topc : 0) + (cI ? rigc : 0) - ((rI & cI) ? pc2 : 0);
                      int nv = 32 * (9 - 3 * rI - 3 * cI + (rI & cI));
                      v1 = nv - 2 * (S01 - corr); }
                    { int rI = rB, cI = cL;
                      int corr = (rI ? botc : 0) + (cI ? lefc : 0) - ((rI & cI) ? pc6 : 0);
                      int nv = 32 * (9 - 3 * rI - 3 * cI + (rI & cI));
                      v2 = nv - 2 * (S10 - corr); }
                    { int rI = rB, cI = cR;
                      int corr = (rI ? botc : 0) + (cI ? rigc : 0) - ((rI & cI) ? pc8 : 0);
                      int nv = 32 * (9 - 3 * rI - 3 * cI + (rI & cI));
                      v3 = nv - 2 * (S11 - corr); }
                    pred = (max(max(v0, v1), max(v2, v3)) >= ic2);
                }
                unsigned long long m = __ballot(pred);
                if (lane == 0)
                    *(uint2*)&s_H2[im][pi + 1][pj + 1][0] =
                        make_uint2((uint32_t)m, (uint32_t)(m >> 32));
            }
        }
    }
    __syncthreads();

    // ---- conv3: lane = (oc 0..15, im 0..3); 49 pos over 4 waves ----
    {
        int oc = lane & 15, im = lane >> 4;
        uint32_t w[18];
#pragma unroll
        for (int k = 0; k < 18; ++k) w[k] = s_W3t[k][oc];
        float bias3 = s_b3[oc];
        int pc[9];
#pragma unroll
        for (int k = 0; k < 9; ++k) pc[k] = __popc(w[2 * k]) + __popc(w[2 * k + 1]);
        int topc = pc[0] + pc[1] + pc[2], botc = pc[6] + pc[7] + pc[8];
        int lefc = pc[0] + pc[3] + pc[6], rigc = pc[2] + pc[5] + pc[8];

        for (int pos = wid; pos < 49; pos += 4) {
            int pi = pos / 7, pj = pos - pi * 7;
            int S = 0;
#pragma unroll
            for (int kh = 0; kh < 3; ++kh)
#pragma unroll
                for (int kw = 0; kw < 3; ++kw) {
                    uint2 cc = *(const uint2*)&s_H2[im][pi + kh][pj + kw][0];
                    int k = kh * 3 + kw;
                    S += __popc(cc.x ^ w[2 * k]) + __popc(cc.y ^ w[2 * k + 1]);
                }
            int v;
            if (pi >= 1 && pi <= 5 && pj >= 1 && pj <= 5) {
                v = 576 - 2 * S;
            } else {
                int rT = (pi == 0), rB = (pi == 6), cL = (pj == 0), cR = (pj == 6);
                int rA = rT | rB, cA = cL | cR;
                int corr = (rT ? topc : 0) + (rB ? botc : 0) +
                           (cL ? lefc : 0) + (cR ? rigc : 0);
                if (rT & cL) corr -= pc[0];
                if (rT & cR) corr -= pc[2];
                if (rB & cL) corr -= pc[6];
                if (rB & cR) corr -= pc[8];
                int nInv = 3 * rA + 3 * cA - (rA & cA);
                v = 64 * (9 - nInv) - 2 * (S - corr);
            }
            float h = fmaxf((float)v + bias3, 0.f);
            h3T[(oc * 49 + pos) * 4096 + img0 + im] = h;
        }
    }
}

// ---------------- fc_stack: fused FC1+FC2+FC3, 16 imgs/block ----------------
// 256 blocks (1/CU). No barriers inside k-loops. h3 in LDS [784][16];
// weights streamed from L2 (quad-shared float4 per kk). LDS region reused
// for fc1/fc2 activations.
__global__ __launch_bounds__(256, 1) void fc_stack(
    const float* __restrict__ h3T, const float* __restrict__ w1T,
    const float* __restrict__ fc1_b,
    const float* __restrict__ w2T, const float* __restrict__ fc2_b,
    const float* __restrict__ fc3_w, const float* __restrict__ fc3_b,
    float* __restrict__ out) {
    __shared__ __align__(16) float s_h[12544];   // [784][16]
    const int t = threadIdx.x;
    const int lane = t & 63, wv = t >> 6;
    const int ng = lane & 15, ig = lane >> 4;    // ig: img-group 0..3
    const int img0 = blockIdx.x * 16;

    // stage h3 (3136 float4s, coalesced 64B per k-row)
    for (int f = t; f < 3136; f += 256) {
        int k = f >> 2, q = (f & 3) * 4;
        *(float4*)&s_h[k * 16 + q] = *(const float4*)&h3T[k * 4096 + img0 + q];
    }
    __syncthreads();

    // ---- FC1: 784 -> 256; thread = (4 n, 4 img) ----
    float acc[4][4] = {{0.f}};
    {
        const int n0 = wv * 64 + ng * 4;
        const float* bp = w1T + n0;
        const float* ap = s_h + ig * 4;
#pragma unroll 8
        for (int k = 0; k < 784; ++k) {
            float4 b = *(const float4*)&bp[k * 256];
            float4 a = *(const float4*)&ap[k * 16];
            acc[0][0] += a.x * b.x; acc[0][1] += a.x * b.y;
            acc[0][2] += a.x * b.z; acc[0][3] += a.x * b.w;
            acc[1][0] += a.y * b.x; acc[1][1] += a.y * b.y;
            acc[1][2] += a.y * b.z; acc[1][3] += a.y * b.w;
            acc[2][0] += a.z * b.x; acc[2][1] += a.z * b.y;
            acc[2][2] += a.z * b.z; acc[2][3] += a.z * b.w;
            acc[3][0] += a.w * b.x; acc[3][1] += a.w * b.y;
            acc[3][2] += a.w * b.z; acc[3][3] += a.w * b.w;
        }
    }
    __syncthreads();            // all s_h reads done; region reusable
    {
        const int n0 = wv * 64 + ng * 4;
#pragma unroll
        for (int jj = 0; jj < 4; ++jj) {
            float bb = fc1_b[n0 + jj];
            float4 v;
            v.x = fmaxf(acc[0][jj] + bb, 0.f);
            v.y = fmaxf(acc[1][jj] + bb, 0.f);
            v.z = fmaxf(acc[2][jj] + bb, 0.f);
            v.w = fmaxf(acc[3][jj] + bb, 0.f);
            *(float4*)&s_h[(n0 + jj) * 16 + ig * 4] = v;   // s_g [256][16]
        }
    }
    __syncthreads();

    // ---- FC2: 256 -> 128; thread = (2 n, 4 img) ----
    float ac2[4][2] = {{0.f}};
    {
        const int n0 = wv * 32 + ng * 2;
        const float* bp = w2T + n0;
        const float* ap = s_h + ig * 4;
#pragma unroll 8
        for (int k = 0; k < 256; ++k) {
            float2 b = *(const float2*)&bp[k * 128];
            float4 a = *(const float4*)&ap[k * 16];
            ac2[0][0] += a.x * b.x; ac2[0][1] += a.x * b.y;
            ac2[1][0] += a.y * b.x; ac2[1][1] += a.y * b.y;
            ac2[2][0] += a.z * b.x; ac2[2][1] += a.z * b.y;
            ac2[3][0] += a.w * b.x; ac2[3][1] += a.w * b.y;
        }
    }
    // s_h2 [128][16] lives at offset 4096 floats — disjoint from s_g reads
    {
        const int n0 = wv * 32 + ng * 2;
#pragma unroll
        for (int jj = 0; jj < 2; ++jj) {
            float bb = fc2_b[n0 + jj];
            float4 v;
            v.x = fmaxf(ac2[0][jj] + bb, 0.f);
            v.y = fmaxf(ac2[1][jj] + bb, 0.f);
            v.z = fmaxf(ac2[2][jj] + bb, 0.f);
            v.w = fmaxf(ac2[3][jj] + bb, 0.f);
            *(float4*)&s_h[4096 + (n0 + jj) * 16 + ig * 4] = v;
        }
    }
    __syncthreads();

    // ---- FC3: 128 -> 10; 160 threads, coalesced 640-B store ----
    if (t < 160) {
        int img = t / 10, n = t - (t / 10) * 10;
        const float* wr = fc3_w + n * 128;
        const float* hp = s_h + 4096 + img;
        float a0 = 0.f, a1 = 0.f, a2 = 0.f, a3 = 0.f;
#pragma unroll 8
        for (int k = 0; k < 128; k += 4) {
            a0 += hp[(k + 0) * 16] * wr[k + 0];
            a1 += hp[(k + 1) * 16] * wr[k + 1];
            a2 += hp[(k + 2) * 16] * wr[k + 2];
            a3 += hp[(k + 3) * 16] * wr[k + 3];
        }
        out[(img0 + img) * 10 + n] = (a0 + a1) + (a2 + a3) + fc3_b[n];
    }
}

extern "C" void kernel_launch(void* const* d_in, const int* in_sizes, int n_in,
                              void* d_out, int out_size, void* d_ws, size_t ws_size,
                              hipStream_t stream) {
    const float* x     = (const float*)d_in[0];
    const float* w1    = (const float*)d_in[1];
    const float* b1    = (const float*)d_in[2];
    const float* w2    = (const float*)d_in[3];
    const float* b2    = (const float*)d_in[4];
    const float* w3    = (const float*)d_in[5];
    const float* b3    = (const float*)d_in[6];
    const float* fc1_w = (const float*)d_in[7];
    const float* fc1_b = (const float*)d_in[8];
    const float* fc2_w = (const float*)d_in[9];
    const float* fc2_b = (const float*)d_in[10];
    const float* fc3_w = (const float*)d_in[11];
    const float* fc3_b = (const float*)d_in[12];
    float* out = (float*)d_out;

    const int B = in_sizes[0] / 784;  // 4096
    char* ws = (char*)d_ws;
    float* w1T = (float*)(ws + OFF_W1T);
    float* w2T = (float*)(ws + OFF_W2T);
    float* h3T = (float*)(ws + OFF_H3T);

    hipLaunchKernelGGL(conv_stack, dim3(B / 4), dim3(256), 0, stream,
                       x, b1, b2, b3, w1, w2, w3, fc1_w, fc2_w, w1T, w2T, h3T);
    hipLaunchKernelGGL(fc_stack, dim3(B / 16), dim3(256), 0, stream,
                       h3T, w1T, fc1_b, w2T, fc2_b, fc3_w, fc3_b, out);
}